// Round 3
// baseline (608.117 us; speedup 1.0000x reference)
//
#include <hip/hip_runtime.h>
#include <hip/hip_bf16.h>

// B=64 batch, T=512 enc timesteps, E=1024 enc hidden, D=1024 dec hidden
// ALL inputs/outputs are FLOAT32 (per reference setup_inputs).
#define BB 64
#define TT 512
#define EE 1024
#define DD 1024
// Fused e-proj GEMM: M = T*B = 32768, N = 2E = 2048, K = E = 1024 (bf16 MFMA)
#define BK 64   // k-tile depth

typedef __attribute__((ext_vector_type(8))) short s16x8;   // 8 bf16 MFMA A/B frag
typedef __attribute__((ext_vector_type(4))) float f32x4;   // MFMA C/D frag

__device__ __forceinline__ float bf2f(unsigned short u) {
    unsigned int x = ((unsigned int)u) << 16;
    return __builtin_bit_cast(float, x);
}
__device__ __forceinline__ unsigned short f2bf(float f) {   // RNE, finite inputs
    unsigned int u = __builtin_bit_cast(unsigned int, f);
    u += 0x7FFF + ((u >> 16) & 1);
    return (unsigned short)(u >> 16);
}
__device__ __forceinline__ float tanh_fast(float x) {
    x = fminf(fmaxf(x, -15.f), 15.f);
    float e = __expf(2.f * x);
    return (e - 1.f) / (e + 1.f);
}

// ---------------------------------------------------------------------------
// Convert enc f32 [T*B*E] -> bf16 (same layout). 32768 blocks.
// ---------------------------------------------------------------------------
__global__ __launch_bounds__(256) void conv_enc_kernel(
    const float4* __restrict__ src, ushort4* __restrict__ dst)
{
    int idx = blockIdx.x * 256 + threadIdx.x;
    float4 v = src[idx];
    ushort4 o;
    o.x = f2bf(v.x); o.y = f2bf(v.y); o.z = f2bf(v.z); o.w = f2bf(v.w);
    dst[idx] = o;
}

// ---------------------------------------------------------------------------
// Convert Wa[:, 1024:2048] f32 -> WaR bf16 [2048][1024]. 2048 blocks.
// ---------------------------------------------------------------------------
__global__ __launch_bounds__(256) void conv_wa_kernel(
    const float* __restrict__ Wa, unsigned short* __restrict__ WaR)
{
    int idx = blockIdx.x * 256 + threadIdx.x;
    int row = idx >> 8;
    int c4  = idx & 255;
    float4 v = *(const float4*)(Wa + (size_t)row * 2048 + 1024 + c4 * 4);
    ushort4 o;
    o.x = f2bf(v.x); o.y = f2bf(v.y); o.z = f2bf(v.z); o.w = f2bf(v.w);
    *(ushort4*)(WaR + (size_t)row * 1024 + c4 * 4) = o;
}

// ---------------------------------------------------------------------------
// hproj[f][b] = hidden[b,:1024] . Wa[f,:1024] + ba[f]   (f-major, f32)
// ---------------------------------------------------------------------------
__global__ __launch_bounds__(256) void hproj_kernel(
    const float* __restrict__ hidden,   // [64,1024]
    const float* __restrict__ Wa,       // [2048,2048]
    const float* __restrict__ ba,       // [2048]
    float* __restrict__ hp)             // [2048*64]
{
    __shared__ float sW[8 * 1024];      // 32 KB
    const int tid  = threadIdx.x;
    const int lane = tid & 63;
    const int wave = tid >> 6;
    const int f0   = blockIdx.x * 8;

#pragma unroll
    for (int i = 0; i < 8; ++i) {
        int idx = i * 256 + tid;
        int fi  = idx >> 8;
        int c4  = idx & 255;
        ((float4*)sW)[idx] = *(const float4*)(Wa + (size_t)(f0 + fi) * 2048 + c4 * 4);
    }
    __syncthreads();

    for (int bi = 0; bi < 16; ++bi) {
        int b = wave * 16 + bi;
        float h[16];
#pragma unroll
        for (int j = 0; j < 16; ++j) h[j] = hidden[b * 1024 + lane + 64 * j];
#pragma unroll
        for (int fi = 0; fi < 8; ++fi) {
            float s = 0.f;
#pragma unroll
            for (int j = 0; j < 16; ++j) s += h[j] * sW[fi * 1024 + lane + 64 * j];
#pragma unroll
            for (int m = 32; m; m >>= 1) s += __shfl_xor(s, m);
            if (lane == 0) hp[(f0 + fi) * 64 + b] = s + ba[f0 + fi];
        }
    }
}

// ---------------------------------------------------------------------------
// Fused e_proj GEMM (bf16 MFMA) + tanh + w2-dot -> scores
//   C[r,f] = sum_k encB[r,k] * WaR[f,k]   (r = t*64+b)
//   scores[b,t] += sum_f tanh(C[r,f] + hp[f][b]) * w2[f]
// 128x128 tile, BK=64, 4 waves each 64x64 (4x4 of 16x16x32 MFMA, 2 k-chunks)
//
// LDS layout (conflict-free by construction): chunk(row, g) [16B = 8 bf16 of
// row `row`, k-group g in 0..7] lives at slot  p*128 + g*16 + (row&15), where
// p = row>>4.  Fragment read for (mi, kk): addr = base + lane*16 — linear in
// lane, so every 8 consecutive lanes sweep all 32 banks. global_load_lds's
// "wave-uniform base + lane*16" constraint is satisfied since slots are
// linear; only the per-lane SOURCE address is permuted.
// grid = (256, 16), block = 256
// ---------------------------------------------------------------------------
__global__ __launch_bounds__(256) void gemm_scores(
    const unsigned short* __restrict__ encB,  // [32768,1024] bf16 (ws)
    const unsigned short* __restrict__ WaR,   // [2048,1024]  bf16 (ws)
    const float* __restrict__ hp,             // [2048*64] f32, f-major
    const float* __restrict__ w2,             // [2048] f32
    float* __restrict__ scores)               // [64*512] f32, zeroed
{
    __shared__ short sA[128 * BK];  // 16 KB
    __shared__ short sB[128 * BK];  // 16 KB
    __shared__ float rowAcc[128];

    const int tid  = threadIdx.x;
    const int bm   = blockIdx.x;   // row tile (r)
    const int bn   = blockIdx.y;   // col tile (f)
    const int lane = tid & 63;
    const int wave = tid >> 6;
    const int wm   = wave >> 1;
    const int wn   = wave & 1;
    const int c    = lane & 15;
    const int quad = lane >> 4;

    f32x4 acc[4][4];
#pragma unroll
    for (int mi = 0; mi < 4; ++mi)
#pragma unroll
        for (int ni = 0; ni < 4; ++ni)
#pragma unroll
            for (int r = 0; r < 4; ++r) acc[mi][ni][r] = 0.f;

    // Per-thread staging decomposition (4 chunks per array per iter):
    // slot s = i*256 + tid ->  p = s>>7, g = (s>>4)&7, rr = s&15
    for (int k0 = 0; k0 < 1024; k0 += BK) {
#pragma unroll
        for (int i = 0; i < 4; ++i) {
            int s   = i * 256 + tid;
            int p   = s >> 7;
            int g   = (s >> 4) & 7;
            int rr  = s & 15;
            int row = p * 16 + rr;
            const unsigned short* ga = encB + (size_t)(bm * 128 + row) * 1024 + k0 + g * 8;
            __builtin_amdgcn_global_load_lds(
                (const __attribute__((address_space(1))) void*)ga,
                (__attribute__((address_space(3))) void*)&sA[s * 8], 16, 0, 0);
            const unsigned short* gb = WaR + (size_t)(bn * 128 + row) * 1024 + k0 + g * 8;
            __builtin_amdgcn_global_load_lds(
                (const __attribute__((address_space(1))) void*)gb,
                (__attribute__((address_space(3))) void*)&sB[s * 8], 16, 0, 0);
        }
        __builtin_amdgcn_s_waitcnt(0);
        __syncthreads();

#pragma unroll
        for (int kk = 0; kk < 2; ++kk) {
            s16x8 aF[4], bF[4];
#pragma unroll
            for (int mi = 0; mi < 4; ++mi)
                aF[mi] = *(const s16x8*)&sA[((wm * 4 + mi) * 128 + kk * 64 + lane) * 8];
#pragma unroll
            for (int ni = 0; ni < 4; ++ni)
                bF[ni] = *(const s16x8*)&sB[((wn * 4 + ni) * 128 + kk * 64 + lane) * 8];

#pragma unroll
            for (int mi = 0; mi < 4; ++mi)
#pragma unroll
                for (int ni = 0; ni < 4; ++ni)
                    acc[mi][ni] = __builtin_amdgcn_mfma_f32_16x16x32_bf16(
                        aF[mi], bF[ni], acc[mi][ni], 0, 0, 0);
        }
        __syncthreads();
    }

    // Epilogue: scores_row += sum_f tanh(C + hp) * w2 over this block's cols.
    float w2v[4];
#pragma unroll
    for (int ni = 0; ni < 4; ++ni) w2v[ni] = w2[bn * 128 + wn * 64 + ni * 16 + c];

    if (tid < 128) rowAcc[tid] = 0.f;
    __syncthreads();

#pragma unroll
    for (int mi = 0; mi < 4; ++mi) {
        int lrow0 = wm * 64 + mi * 16 + quad * 4;       // quad*4-aligned
        int b0    = (bm * 128 + lrow0) & 63;            // float4-aligned
        f32x4 hp4[4];
#pragma unroll
        for (int ni = 0; ni < 4; ++ni)
            hp4[ni] = *(const f32x4*)&hp[(bn * 128 + wn * 64 + ni * 16 + c) * 64 + b0];
#pragma unroll
        for (int r = 0; r < 4; ++r) {
            float s = 0.f;
#pragma unroll
            for (int ni = 0; ni < 4; ++ni)
                s += tanh_fast(acc[mi][ni][r] + hp4[ni][r]) * w2v[ni];
            s += __shfl_xor(s, 1);
            s += __shfl_xor(s, 2);
            s += __shfl_xor(s, 4);
            s += __shfl_xor(s, 8);
            if (c == 0) atomicAdd(&rowAcc[lrow0 + r], s);
        }
    }
    __syncthreads();
    if (tid < 128) {
        int grow = bm * 128 + tid;
        int b = grow & 63;
        int t = grow >> 6;
        atomicAdd(&scores[b * TT + t], rowAcc[tid]);
    }
}

// ---------------------------------------------------------------------------
// Softmax over T per batch row, in-place on scores [64][512]
// ---------------------------------------------------------------------------
__global__ __launch_bounds__(256) void softmax_kernel(float* __restrict__ scores)
{
    __shared__ float wmax[4];
    __shared__ float wsum[4];
    const int b   = blockIdx.x;
    const int tid = threadIdx.x;
    float* row = scores + b * TT;

    float v0 = row[tid], v1 = row[tid + 256];
    float m = fmaxf(v0, v1);
#pragma unroll
    for (int s = 32; s; s >>= 1) m = fmaxf(m, __shfl_xor(m, s));
    if ((tid & 63) == 0) wmax[tid >> 6] = m;
    __syncthreads();
    m = fmaxf(fmaxf(wmax[0], wmax[1]), fmaxf(wmax[2], wmax[3]));

    float e0 = __expf(v0 - m), e1 = __expf(v1 - m);
    float s = e0 + e1;
#pragma unroll
    for (int t = 32; t; t >>= 1) s += __shfl_xor(s, t);
    if ((tid & 63) == 0) wsum[tid >> 6] = s;
    __syncthreads();
    float inv = 1.f / (wsum[0] + wsum[1] + wsum[2] + wsum[3]);
    row[tid]       = e0 * inv;
    row[tid + 256] = e1 * inv;
}

// ---------------------------------------------------------------------------
// applied partials: part[tc][b][e] = sum_{t in chunk tc} w[b,t]*enc[t,b,e]
// grid = (16 tc, 64 b), block = 256: 128 e-owners x 2 t-halves
// ---------------------------------------------------------------------------
__global__ __launch_bounds__(256) void applied_part_kernel(
    const unsigned short* __restrict__ encB,  // bf16 copy
    const float* __restrict__ w,              // [64,512] weights
    float* __restrict__ part)                 // [16][64][1024]
{
    __shared__ float red[128 * 8];
    const int tc  = blockIdx.x;
    const int b   = blockIdx.y;
    const int tid = threadIdx.x;
    const int eo  = tid & 127;
    const int th  = tid >> 7;
    const int e0  = eo * 8;

    float a[8];
#pragma unroll
    for (int j = 0; j < 8; ++j) a[j] = 0.f;

    for (int it = 0; it < 16; ++it) {
        int t = tc * 32 + th * 16 + it;
        float wt = w[b * TT + t];
        s16x8 v = *(const s16x8*)(encB + ((size_t)(t * BB + b)) * EE + e0);
#pragma unroll
        for (int j = 0; j < 8; ++j) a[j] += wt * bf2f((unsigned short)v[j]);
    }
    if (th == 1) {
#pragma unroll
        for (int j = 0; j < 8; ++j) red[eo * 8 + j] = a[j];
    }
    __syncthreads();
    if (th == 0) {
        float* dst = part + ((size_t)tc * 64 + b) * 1024 + e0;
#pragma unroll
        for (int j = 0; j < 8; ++j) dst[j] = a[j] + red[eo * 8 + j];
    }
}

// reduce 16 partials -> applied (output 1, f32) at out+65536
__global__ __launch_bounds__(256) void applied_reduce_kernel(
    const float* __restrict__ part, float* __restrict__ out_applied)
{
    int idx = blockIdx.x * 256 + threadIdx.x;
    float s = 0.f;
#pragma unroll
    for (int tc = 0; tc < 16; ++tc) s += part[tc * 65536 + idx];
    out_applied[idx] = s;
}

// ---------------------------------------------------------------------------
// out[b,d] = tanh(dec[b].Wc[d,:1024] + applied[b].Wc[d,1024:] + bc[d])
// ---------------------------------------------------------------------------
__global__ __launch_bounds__(256) void combine_kernel(
    const float* __restrict__ dec,       // [64,1024]
    const float* applied,                // [64,1024] (= out+65536)
    const float* __restrict__ Wc,        // [1024,2048]
    const float* __restrict__ bc,        // [1024]
    float* out0)                         // first 65536 of d_out
{
    const int g    = blockIdx.x * 4 + (threadIdx.x >> 6);
    const int lane = threadIdx.x & 63;
    const int d    = g >> 6;
    const int b    = g & 63;

    const float4* wc4 = (const float4*)Wc + (size_t)d * 512;
    const float4* de4 = (const float4*)dec + (size_t)b * 256;
    const float4* ap4 = (const float4*)applied + (size_t)b * 256;

    float s = 0.f;
#pragma unroll
    for (int j = 0; j < 4; ++j) {
        float4 a = de4[j * 64 + lane];
        float4 wv = wc4[j * 64 + lane];
        s += a.x * wv.x + a.y * wv.y + a.z * wv.z + a.w * wv.w;
    }
#pragma unroll
    for (int j = 0; j < 4; ++j) {
        float4 a = ap4[j * 64 + lane];
        float4 wv = wc4[256 + j * 64 + lane];
        s += a.x * wv.x + a.y * wv.y + a.z * wv.z + a.w * wv.w;
    }
#pragma unroll
    for (int m = 32; m; m >>= 1) s += __shfl_xor(s, m);
    if (lane == 0) out0[b * DD + d] = tanh_fast(s + bc[d]);
}

// ---------------------------------------------------------------------------
extern "C" void kernel_launch(void* const* d_in, const int* in_sizes, int n_in,
                              void* d_out, int out_size, void* d_ws, size_t ws_size,
                              hipStream_t stream) {
    const float* hidden = (const float*)d_in[0]; // [64,1024]
    const float* dec    = (const float*)d_in[1]; // [64,1024]
    const float* enc    = (const float*)d_in[2]; // [512,64,1024]
    const float* Wa     = (const float*)d_in[3]; // [2048,2048]
    const float* ba     = (const float*)d_in[4]; // [2048]
    const float* w2     = (const float*)d_in[5]; // [2048]
    // d_in[6] = b2: uniform shift of scores -> softmax-invariant, unused.
    const float* Wc     = (const float*)d_in[7]; // [1024,2048]
    const float* bc     = (const float*)d_in[8]; // [1024]
    float* out = (float*)d_out;                  // [64*1024 out | 64*1024 applied]

    unsigned short* encB = (unsigned short*)d_ws;               // 33554432 bf16
    unsigned short* WaR  = encB + (size_t)33554432;             //  2097152 bf16
    float* hp     = (float*)(WaR + (size_t)2097152);            //   131072 f32
    float* scores = hp + 131072;                                //    32768 f32
    float* part   = scores + 32768;                             //  1048576 f32

    hipMemsetAsync(scores, 0, BB * TT * sizeof(float), stream);
    conv_enc_kernel<<<32768, 256, 0, stream>>>((const float4*)enc, (ushort4*)encB);
    conv_wa_kernel<<<2048, 256, 0, stream>>>(Wa, WaR);
    hproj_kernel<<<256, 256, 0, stream>>>(hidden, Wa, ba, hp);
    dim3 g2(256, 16);
    gemm_scores<<<g2, 256, 0, stream>>>(encB, WaR, hp, w2, scores);
    softmax_kernel<<<BB, 256, 0, stream>>>(scores);
    dim3 g3(16, 64);
    applied_part_kernel<<<g3, 256, 0, stream>>>(encB, scores, part);
    applied_reduce_kernel<<<256, 256, 0, stream>>>(part, out + BB * DD);
    combine_kernel<<<16384, 256, 0, stream>>>(dec, out + BB * DD, Wc, bc, out);
}

// Round 4
// 546.637 us; speedup vs baseline: 1.1125x; 1.1125x over previous
//
#include <hip/hip_runtime.h>
#include <hip/hip_bf16.h>

// B=64 batch, T=512 enc timesteps, E=1024 enc hidden, D=1024 dec hidden
// ALL inputs/outputs are FLOAT32 (per reference setup_inputs).
#define BB 64
#define TT 512
#define EE 1024
#define DD 1024
// Fused e-proj GEMM: M = T*B = 32768, N = 2E = 2048, K = E = 1024 (bf16 MFMA)
#define BK 64   // k-tile depth

typedef __attribute__((ext_vector_type(8))) short s16x8;   // 8 bf16 MFMA A/B frag
typedef __attribute__((ext_vector_type(4))) float f32x4;   // MFMA C/D frag

__device__ __forceinline__ float bf2f(unsigned short u) {
    unsigned int x = ((unsigned int)u) << 16;
    return __builtin_bit_cast(float, x);
}
__device__ __forceinline__ unsigned short f2bf(float f) {   // RNE, finite inputs
    unsigned int u = __builtin_bit_cast(unsigned int, f);
    u += 0x7FFF + ((u >> 16) & 1);
    return (unsigned short)(u >> 16);
}
__device__ __forceinline__ float tanh_fast(float x) {
    x = fminf(fmaxf(x, -15.f), 15.f);
    float e = __expf(2.f * x);
    return (e - 1.f) / (e + 1.f);
}

// Tile-order slot for chunk (row 0..127, g 0..7):  [8 bf16 chunks of 16B]
//   slot = (row>>4)*128 + (g>>2)*64 + (g&3)*16 + (row&15)
// This is exactly the order the GEMM's lane-linear fragment reads expect:
//   A-frag (m16, kk): slot = m16*128 + kk*64 + lane  -> lane holds
//   A[row=m16*16+(lane&15)][k=kk*32+(lane>>4)*8 ..+8]
__device__ __forceinline__ int tile_slot(int row, int g) {
    return (row >> 4) * 128 + (g >> 2) * 64 + (g & 3) * 16 + (row & 15);
}

// ---------------------------------------------------------------------------
// enc f32 [32768,1024] -> encS bf16 tiled: tile (tm 0..255, tk 0..15) of
// 128 rows x 64 k stored as 1024 chunks in tile_slot order (16 KB/tile).
// grid = (256, 16), block = 256. LDS transpose for coalescing on both ends.
// ---------------------------------------------------------------------------
__global__ __launch_bounds__(256) void conv_encS_kernel(
    const float* __restrict__ enc, unsigned short* __restrict__ encS)
{
    __shared__ short tileL[1024 * 8];   // 16 KB
    const int tm  = blockIdx.x;
    const int tk  = blockIdx.y;
    const int tid = threadIdx.x;

#pragma unroll
    for (int it = 0; it < 4; ++it) {
        int cidx = it * 256 + tid;       // chunk id
        int row  = cidx >> 3;            // 0..127
        int g    = cidx & 7;             // 0..7
        const float* src = enc + (size_t)(tm * 128 + row) * 1024 + tk * 64 + g * 8;
        float4 v0 = ((const float4*)src)[0];
        float4 v1 = ((const float4*)src)[1];
        short c[8];
        c[0] = (short)f2bf(v0.x); c[1] = (short)f2bf(v0.y);
        c[2] = (short)f2bf(v0.z); c[3] = (short)f2bf(v0.w);
        c[4] = (short)f2bf(v1.x); c[5] = (short)f2bf(v1.y);
        c[6] = (short)f2bf(v1.z); c[7] = (short)f2bf(v1.w);
        *(s16x8*)&tileL[tile_slot(row, g) * 8] = *(s16x8*)c;
    }
    __syncthreads();
    unsigned short* dst = encS + ((size_t)tm * 16 + tk) * 8192;
#pragma unroll
    for (int it = 0; it < 4; ++it) {
        int s = it * 256 + tid;
        *(s16x8*)&dst[s * 8] = *(const s16x8*)&tileL[s * 8];
    }
}

// ---------------------------------------------------------------------------
// Wa[:,1024:2048] f32 -> WaS bf16 tiled: tile (tn 0..15, tk 0..15), same
// tile_slot order (rows = f within 128-col tile). grid = (16,16).
// ---------------------------------------------------------------------------
__global__ __launch_bounds__(256) void conv_waS_kernel(
    const float* __restrict__ Wa, unsigned short* __restrict__ WaS)
{
    __shared__ short tileL[1024 * 8];
    const int tn  = blockIdx.x;
    const int tk  = blockIdx.y;
    const int tid = threadIdx.x;

#pragma unroll
    for (int it = 0; it < 4; ++it) {
        int cidx = it * 256 + tid;
        int row  = cidx >> 3;            // f within tile
        int g    = cidx & 7;
        const float* src = Wa + (size_t)(tn * 128 + row) * 2048 + 1024 + tk * 64 + g * 8;
        float4 v0 = ((const float4*)src)[0];
        float4 v1 = ((const float4*)src)[1];
        short c[8];
        c[0] = (short)f2bf(v0.x); c[1] = (short)f2bf(v0.y);
        c[2] = (short)f2bf(v0.z); c[3] = (short)f2bf(v0.w);
        c[4] = (short)f2bf(v1.x); c[5] = (short)f2bf(v1.y);
        c[6] = (short)f2bf(v1.z); c[7] = (short)f2bf(v1.w);
        *(s16x8*)&tileL[tile_slot(row, g) * 8] = *(s16x8*)c;
    }
    __syncthreads();
    unsigned short* dst = WaS + ((size_t)tn * 16 + tk) * 8192;
#pragma unroll
    for (int it = 0; it < 4; ++it) {
        int s = it * 256 + tid;
        *(s16x8*)&dst[s * 8] = *(const s16x8*)&tileL[s * 8];
    }
}

// ---------------------------------------------------------------------------
// hproj[f][b] = hidden[b,:1024] . Wa[f,:1024] + ba[f]   (f-major, f32)
// ---------------------------------------------------------------------------
__global__ __launch_bounds__(256) void hproj_kernel(
    const float* __restrict__ hidden,   // [64,1024]
    const float* __restrict__ Wa,       // [2048,2048]
    const float* __restrict__ ba,       // [2048]
    float* __restrict__ hp)             // [2048*64]
{
    __shared__ float sW[8 * 1024];      // 32 KB
    const int tid  = threadIdx.x;
    const int lane = tid & 63;
    const int wave = tid >> 6;
    const int f0   = blockIdx.x * 8;

#pragma unroll
    for (int i = 0; i < 8; ++i) {
        int idx = i * 256 + tid;
        int fi  = idx >> 8;
        int c4  = idx & 255;
        ((float4*)sW)[idx] = *(const float4*)(Wa + (size_t)(f0 + fi) * 2048 + c4 * 4);
    }
    __syncthreads();

    for (int bi = 0; bi < 16; ++bi) {
        int b = wave * 16 + bi;
        float h[16];
#pragma unroll
        for (int j = 0; j < 16; ++j) h[j] = hidden[b * 1024 + lane + 64 * j];
#pragma unroll
        for (int fi = 0; fi < 8; ++fi) {
            float s = 0.f;
#pragma unroll
            for (int j = 0; j < 16; ++j) s += h[j] * sW[fi * 1024 + lane + 64 * j];
#pragma unroll
            for (int m = 32; m; m >>= 1) s += __shfl_xor(s, m);
            if (lane == 0) hp[(f0 + fi) * 64 + b] = s + ba[f0 + fi];
        }
    }
}

// ---------------------------------------------------------------------------
// Fused e_proj GEMM (bf16 MFMA) + tanh + w2-dot -> scores
// Inputs are PRE-SWIZZLED tiles: staging loads are contiguous 1KB/wave-instr,
// LDS writes lane-linear (global_load_lds), fragment reads lane-linear
// (conflict-free, verified R3: SQ_LDS_BANK_CONFLICT = 0).
// grid = (256 bm, 16 bn), block = 256
// ---------------------------------------------------------------------------
__global__ __launch_bounds__(256) void gemm_scores(
    const unsigned short* __restrict__ encS,  // tiled bf16 (ws)
    const unsigned short* __restrict__ WaS,   // tiled bf16 (ws)
    const float* __restrict__ hp,             // [2048*64] f32, f-major
    const float* __restrict__ w2,             // [2048] f32
    float* __restrict__ scores)               // [64*512] f32, zeroed
{
    __shared__ short sA[128 * BK];  // 16 KB
    __shared__ short sB[128 * BK];  // 16 KB
    __shared__ float rowAcc[128];

    const int tid  = threadIdx.x;
    const int bm   = blockIdx.x;
    const int bn   = blockIdx.y;
    const int lane = tid & 63;
    const int wave = tid >> 6;
    const int wm   = wave >> 1;
    const int wn   = wave & 1;
    const int c    = lane & 15;
    const int quad = lane >> 4;

    f32x4 acc[4][4];
#pragma unroll
    for (int mi = 0; mi < 4; ++mi)
#pragma unroll
        for (int ni = 0; ni < 4; ++ni)
#pragma unroll
            for (int r = 0; r < 4; ++r) acc[mi][ni][r] = 0.f;

    for (int kt = 0; kt < 16; ++kt) {
        const unsigned short* at = encS + ((size_t)bm * 16 + kt) * 8192;
        const unsigned short* bt = WaS  + ((size_t)bn * 16 + kt) * 8192;
#pragma unroll
        for (int i = 0; i < 4; ++i) {
            int s = i * 256 + tid;
            __builtin_amdgcn_global_load_lds(
                (const __attribute__((address_space(1))) void*)(at + s * 8),
                (__attribute__((address_space(3))) void*)&sA[s * 8], 16, 0, 0);
            __builtin_amdgcn_global_load_lds(
                (const __attribute__((address_space(1))) void*)(bt + s * 8),
                (__attribute__((address_space(3))) void*)&sB[s * 8], 16, 0, 0);
        }
        __builtin_amdgcn_s_waitcnt(0);
        __syncthreads();

#pragma unroll
        for (int kk = 0; kk < 2; ++kk) {
            s16x8 aF[4], bF[4];
#pragma unroll
            for (int mi = 0; mi < 4; ++mi)
                aF[mi] = *(const s16x8*)&sA[((wm * 4 + mi) * 128 + kk * 64 + lane) * 8];
#pragma unroll
            for (int ni = 0; ni < 4; ++ni)
                bF[ni] = *(const s16x8*)&sB[((wn * 4 + ni) * 128 + kk * 64 + lane) * 8];

#pragma unroll
            for (int mi = 0; mi < 4; ++mi)
#pragma unroll
                for (int ni = 0; ni < 4; ++ni)
                    acc[mi][ni] = __builtin_amdgcn_mfma_f32_16x16x32_bf16(
                        aF[mi], bF[ni], acc[mi][ni], 0, 0, 0);
        }
        __syncthreads();
    }

    // Epilogue: scores_row += sum_f tanh(C + hp) * w2 over this block's cols.
    float w2v[4];
#pragma unroll
    for (int ni = 0; ni < 4; ++ni) w2v[ni] = w2[bn * 128 + wn * 64 + ni * 16 + c];

    if (tid < 128) rowAcc[tid] = 0.f;
    __syncthreads();

#pragma unroll
    for (int mi = 0; mi < 4; ++mi) {
        int lrow0 = wm * 64 + mi * 16 + quad * 4;       // quad*4-aligned
        int b0    = (bm * 128 + lrow0) & 63;            // float4-aligned
        f32x4 hp4[4];
#pragma unroll
        for (int ni = 0; ni < 4; ++ni)
            hp4[ni] = *(const f32x4*)&hp[(bn * 128 + wn * 64 + ni * 16 + c) * 64 + b0];
#pragma unroll
        for (int r = 0; r < 4; ++r) {
            float s = 0.f;
#pragma unroll
            for (int ni = 0; ni < 4; ++ni)
                s += tanh_fast(acc[mi][ni][r] + hp4[ni][r]) * w2v[ni];
            s += __shfl_xor(s, 1);
            s += __shfl_xor(s, 2);
            s += __shfl_xor(s, 4);
            s += __shfl_xor(s, 8);
            if (c == 0) atomicAdd(&rowAcc[lrow0 + r], s);
        }
    }
    __syncthreads();
    if (tid < 128) {
        int grow = bm * 128 + tid;
        int b = grow & 63;
        int t = grow >> 6;
        atomicAdd(&scores[b * TT + t], rowAcc[tid]);
    }
}

// ---------------------------------------------------------------------------
// Softmax over T per batch row, in-place on scores [64][512]
// ---------------------------------------------------------------------------
__global__ __launch_bounds__(256) void softmax_kernel(float* __restrict__ scores)
{
    __shared__ float wmax[4];
    __shared__ float wsum[4];
    const int b   = blockIdx.x;
    const int tid = threadIdx.x;
    float* row = scores + b * TT;

    float v0 = row[tid], v1 = row[tid + 256];
    float m = fmaxf(v0, v1);
#pragma unroll
    for (int s = 32; s; s >>= 1) m = fmaxf(m, __shfl_xor(m, s));
    if ((tid & 63) == 0) wmax[tid >> 6] = m;
    __syncthreads();
    m = fmaxf(fmaxf(wmax[0], wmax[1]), fmaxf(wmax[2], wmax[3]));

    float e0 = __expf(v0 - m), e1 = __expf(v1 - m);
    float s = e0 + e1;
#pragma unroll
    for (int t = 32; t; t >>= 1) s += __shfl_xor(s, t);
    if ((tid & 63) == 0) wsum[tid >> 6] = s;
    __syncthreads();
    float inv = 1.f / (wsum[0] + wsum[1] + wsum[2] + wsum[3]);
    row[tid]       = e0 * inv;
    row[tid + 256] = e1 * inv;
}

// ---------------------------------------------------------------------------
// applied partials from ORIGINAL f32 enc (coalesced 4KB rows):
// part[tc][b][e] = sum_{t in chunk tc} w[b,t]*enc[t,b,e]
// grid = (16 tc, 64 b), block = 256: 128 e-owners x 2 t-halves
// ---------------------------------------------------------------------------
__global__ __launch_bounds__(256) void applied_part_kernel(
    const float* __restrict__ enc,            // [T,B,E] f32
    const float* __restrict__ w,              // [64,512] weights
    float* __restrict__ part)                 // [16][64][1024]
{
    __shared__ float red[128 * 8];
    const int tc  = blockIdx.x;
    const int b   = blockIdx.y;
    const int tid = threadIdx.x;
    const int eo  = tid & 127;
    const int th  = tid >> 7;
    const int e0  = eo * 8;

    float a[8];
#pragma unroll
    for (int j = 0; j < 8; ++j) a[j] = 0.f;

    for (int it = 0; it < 16; ++it) {
        int t = tc * 32 + th * 16 + it;
        float wt = w[b * TT + t];
        const float* src = enc + ((size_t)(t * BB + b)) * EE + e0;
        float4 v0 = ((const float4*)src)[0];
        float4 v1 = ((const float4*)src)[1];
        a[0] += wt * v0.x; a[1] += wt * v0.y; a[2] += wt * v0.z; a[3] += wt * v0.w;
        a[4] += wt * v1.x; a[5] += wt * v1.y; a[6] += wt * v1.z; a[7] += wt * v1.w;
    }
    if (th == 1) {
#pragma unroll
        for (int j = 0; j < 8; ++j) red[eo * 8 + j] = a[j];
    }
    __syncthreads();
    if (th == 0) {
        float* dst = part + ((size_t)tc * 64 + b) * 1024 + e0;
#pragma unroll
        for (int j = 0; j < 8; ++j) dst[j] = a[j] + red[eo * 8 + j];
    }
}

// reduce 16 partials -> applied (output 1, f32) at out+65536
__global__ __launch_bounds__(256) void applied_reduce_kernel(
    const float* __restrict__ part, float* __restrict__ out_applied)
{
    int idx = blockIdx.x * 256 + threadIdx.x;
    float s = 0.f;
#pragma unroll
    for (int tc = 0; tc < 16; ++tc) s += part[tc * 65536 + idx];
    out_applied[idx] = s;
}

// ---------------------------------------------------------------------------
// out[b,d] = tanh(dec[b].Wc[d,:1024] + applied[b].Wc[d,1024:] + bc[d])
// ---------------------------------------------------------------------------
__global__ __launch_bounds__(256) void combine_kernel(
    const float* __restrict__ dec,       // [64,1024]
    const float* applied,                // [64,1024] (= out+65536)
    const float* __restrict__ Wc,        // [1024,2048]
    const float* __restrict__ bc,        // [1024]
    float* out0)                         // first 65536 of d_out
{
    const int g    = blockIdx.x * 4 + (threadIdx.x >> 6);
    const int lane = threadIdx.x & 63;
    const int d    = g >> 6;
    const int b    = g & 63;

    const float4* wc4 = (const float4*)Wc + (size_t)d * 512;
    const float4* de4 = (const float4*)dec + (size_t)b * 256;
    const float4* ap4 = (const float4*)applied + (size_t)b * 256;

    float s = 0.f;
#pragma unroll
    for (int j = 0; j < 4; ++j) {
        float4 a = de4[j * 64 + lane];
        float4 wv = wc4[j * 64 + lane];
        s += a.x * wv.x + a.y * wv.y + a.z * wv.z + a.w * wv.w;
    }
#pragma unroll
    for (int j = 0; j < 4; ++j) {
        float4 a = ap4[j * 64 + lane];
        float4 wv = wc4[256 + j * 64 + lane];
        s += a.x * wv.x + a.y * wv.y + a.z * wv.z + a.w * wv.w;
    }
#pragma unroll
    for (int m = 32; m; m >>= 1) s += __shfl_xor(s, m);
    if (lane == 0) out0[b * DD + d] = tanh_fast(s + bc[d]);
}

// ---------------------------------------------------------------------------
extern "C" void kernel_launch(void* const* d_in, const int* in_sizes, int n_in,
                              void* d_out, int out_size, void* d_ws, size_t ws_size,
                              hipStream_t stream) {
    const float* hidden = (const float*)d_in[0]; // [64,1024]
    const float* dec    = (const float*)d_in[1]; // [64,1024]
    const float* enc    = (const float*)d_in[2]; // [512,64,1024]
    const float* Wa     = (const float*)d_in[3]; // [2048,2048]
    const float* ba     = (const float*)d_in[4]; // [2048]
    const float* w2     = (const float*)d_in[5]; // [2048]
    // d_in[6] = b2: uniform shift of scores -> softmax-invariant, unused.
    const float* Wc     = (const float*)d_in[7]; // [1024,2048]
    const float* bc     = (const float*)d_in[8]; // [1024]
    float* out = (float*)d_out;                  // [64*1024 out | 64*1024 applied]

    unsigned short* encS = (unsigned short*)d_ws;               // 33554432 bf16 (tiled)
    unsigned short* WaS  = encS + (size_t)33554432;             //  2097152 bf16 (tiled)
    float* hp     = (float*)(WaS + (size_t)2097152);            //   131072 f32
    float* scores = hp + 131072;                                //    32768 f32
    float* part   = scores + 32768;                             //  1048576 f32

    hipMemsetAsync(scores, 0, BB * TT * sizeof(float), stream);
    dim3 gc(256, 16);
    conv_encS_kernel<<<gc, 256, 0, stream>>>(enc, encS);
    dim3 gw(16, 16);
    conv_waS_kernel<<<gw, 256, 0, stream>>>(Wa, WaS);
    hproj_kernel<<<256, 256, 0, stream>>>(hidden, Wa, ba, hp);
    dim3 g2(256, 16);
    gemm_scores<<<g2, 256, 0, stream>>>(encS, WaS, hp, w2, scores);
    softmax_kernel<<<BB, 256, 0, stream>>>(scores);
    dim3 g3(16, 64);
    applied_part_kernel<<<g3, 256, 0, stream>>>(enc, scores, part);
    applied_reduce_kernel<<<256, 256, 0, stream>>>(part, out + BB * DD);
    combine_kernel<<<16384, 256, 0, stream>>>(dec, out + BB * DD, Wc, bc, out);
}